// Round 4
// baseline (213.199 us; speedup 1.0000x reference)
//
#include <hip/hip_runtime.h>
#include <math.h>

#define BB 2
#define NN 8192
#define CI 64
#define CP 64
#define HH 128
#define WW 128
#define DD 32
#define CF 128
#define SPLITM 8
#define SPLITN 4

typedef __bf16 bf16_t;
typedef __bf16 bf16x8 __attribute__((ext_vector_type(8)));
typedef __bf16 bf16x4 __attribute__((ext_vector_type(4)));
typedef float f32x4 __attribute__((ext_vector_type(4)));

#define SQ_L2E 1.2011224087864498f   /* sqrt(log2(e)) */

__device__ __forceinline__ float fexp2(float x) { return __builtin_amdgcn_exp2f(x); }

__device__ __forceinline__ bf16x8 pack8(float a0,float a1,float a2,float a3,
                                        float b0,float b1,float b2,float b3){
    bf16x8 r;
    r[0]=(bf16_t)a0; r[1]=(bf16_t)a1; r[2]=(bf16_t)a2; r[3]=(bf16_t)a3;
    r[4]=(bf16_t)b0; r[5]=(bf16_t)b1; r[6]=(bf16_t)b2; r[7]=(bf16_t)b3;
    return r;
}

__device__ __forceinline__ bf16x8 ld_av(const bf16_t* p){
    bf16x4 lo = *(const bf16x4*)p;
    bf16x4 hi = *(const bf16x4*)(p + 16);
    bf16x8 r;
    r[0]=lo[0];r[1]=lo[1];r[2]=lo[2];r[3]=lo[3];
    r[4]=hi[0];r[5]=hi[1];r[6]=hi[2];r[7]=hi[3];
    return r;
}

// prep: convert t_w to bf16
__global__ __launch_bounds__(256) void k_prep(const float* __restrict__ tw, bf16_t* __restrict__ twb) {
    int i = blockIdx.x * 256 + threadIdx.x;
    if (i < CP * CP) twb[i] = (bf16_t)tw[i];
}

// transpose img [B][64][HW] -> imgT [B][HW][64] so per-point channel gathers coalesce
__global__ __launch_bounds__(256) void k_timg(const float* __restrict__ img, float* __restrict__ imgT) {
    __shared__ float tile[64][65];
    int b = blockIdx.y;
    int pos0 = blockIdx.x * 64;
    int tid = threadIdx.x;
    int q = tid >> 6, r = tid & 63;
    const float* src = img + (size_t)b * CI * (HH * WW);
#pragma unroll
    for (int cc = 0; cc < 16; ++cc) {
        int c = cc * 4 + q;
        tile[c][r] = src[(size_t)c * (HH * WW) + pos0 + r];
    }
    __syncthreads();
    float* dst = imgT + ((size_t)b * (HH * WW) + pos0) * 64;
#pragma unroll
    for (int pp = 0; pp < 16; ++pp) {
        int pos = pp * 4 + q;
        dst[(size_t)pos * 64 + r] = tile[r][pos];
    }
}

// K1: bilinear gather (coalesced via imgT) + Q proj (scaled bf16) + V proj (bf16 c-major)
__global__ __launch_bounds__(256) void k_fuse(
    const float* __restrict__ pts_img, const float* __restrict__ imgT,
    const float* __restrict__ pfeat, const float* __restrict__ qkw,
    const float* __restrict__ vw, const float* __restrict__ vb,
    bf16_t* __restrict__ Qb, bf16_t* __restrict__ XVb)
{
    __shared__ float qk_l[DD * 129];
    __shared__ float vw_l[CP * 65];
    __shared__ float fus[16][CF];
    __shared__ bf16_t xvout[64][20];
    int tid = threadIdx.x;
    for (int i = tid; i < DD * CF; i += 256) qk_l[(i >> 7) * 129 + (i & 127)] = qkw[i];
    for (int i = tid; i < CP * CP; i += 256) vw_l[(i >> 6) * 65 + (i & 63)] = vw[i];

    int w = tid >> 6, l = tid & 63;
    int p0 = blockIdx.x * 16;
    int bb = p0 / NN, n0 = p0 % NN;

#pragma unroll
    for (int i = 0; i < 4; ++i) {
        int pt = i * 4 + w;
        int n = n0 + pt;
        float x = pts_img[(size_t)(p0 + pt) * 2 + 0];
        float y = pts_img[(size_t)(p0 + pt) * 2 + 1];
        float ix = (x + 1.f) * 0.5f * WW - 0.5f;
        float iy = (y + 1.f) * 0.5f * HH - 0.5f;
        float x0 = floorf(ix), y0 = floorf(iy);
        float wx1 = ix - x0, wx0 = 1.f - wx1;
        float wy1 = iy - y0, wy0 = 1.f - wy1;
        int xi0 = (int)x0, yi0 = (int)y0;
        const float* base = imgT + (size_t)bb * (HH * WW) * 64 + l;
        float iv = 0.f;
#pragma unroll
        for (int cr = 0; cr < 4; ++cr) {
            int xi = xi0 + (cr & 1), yi = yi0 + (cr >> 1);
            float wgt = ((cr & 1) ? wx1 : wx0) * ((cr >> 1) ? wy1 : wy0);
            bool v = (xi >= 0) & (xi <= WW - 1) & (yi >= 0) & (yi <= HH - 1);
            int cx = min(max(xi, 0), WW - 1), cy = min(max(yi, 0), HH - 1);
            float s = base[((size_t)cy * WW + cx) * 64];
            iv += (v ? s : 0.f) * wgt;
        }
        float pv = pfeat[((size_t)bb * CP + l) * NN + n];
        fus[pt][l] = iv;
        fus[pt][64 + l] = pv;
    }
    __syncthreads();
#pragma unroll
    for (int i = 0; i < 4; ++i) {
        int pt = i * 4 + w;
        int n = n0 + pt;
        {
            int qo = l & 31, kh = l >> 5;
            float acc = 0.f;
            const float* qr = &qk_l[qo * 129 + kh * 64];
            const float* fp = &fus[pt][kh * 64];
#pragma unroll
            for (int k = 0; k < 64; ++k) acc += qr[k] * fp[k];
            acc += __shfl_xor(acc, 32);
            if (kh == 0) Qb[((size_t)bb * NN + n) * DD + qo] = (bf16_t)(acc * SQ_L2E);
        }
        {
            float acc = vb[l];
            const float* vr = &vw_l[l * 65];
            const float* fp = &fus[pt][64];
#pragma unroll
            for (int k = 0; k < CP; ++k) acc += vr[k] * fp[k];
            xvout[l][pt] = (bf16_t)acc;
        }
    }
    __syncthreads();
    {
        int c = tid >> 2, seg = (tid & 3) * 4;
        bf16x4 vv;
        vv[0] = xvout[c][seg + 0];
        vv[1] = xvout[c][seg + 1];
        vv[2] = xvout[c][seg + 2];
        vv[3] = xvout[c][seg + 3];
        *(bf16x4*)&XVb[((size_t)bb * CP + c) * NN + n0 + seg] = vv;
    }
}

// K2: rowsum[n] = sum_m exp2(E[n,m]) (no max; exp2 headroom). m-split + atomics.
__global__ __launch_bounds__(256) void k_rowsum(
    const bf16_t* __restrict__ Qb, float* __restrict__ rowsumG)
{
    int b = blockIdx.z;
    int n0 = blockIdx.x * 64;
    int mchunk = blockIdx.y * (NN / SPLITM);
    int tid = threadIdx.x;
    int wv = tid >> 6, l = tid & 63;
    int g = l >> 4, c16 = l & 15;
    const bf16x8* Qv = (const bf16x8*)(Qb + (size_t)b * NN * DD);
    f32x4 z = {0.f, 0.f, 0.f, 0.f};

    bf16x8 A0 = Qv[(size_t)(n0 +  0 + c16) * 4 + g];
    bf16x8 A1 = Qv[(size_t)(n0 + 16 + c16) * 4 + g];
    bf16x8 A2 = Qv[(size_t)(n0 + 32 + c16) * 4 + g];
    bf16x8 A3 = Qv[(size_t)(n0 + 48 + c16) * 4 + g];

    float rs[4][4];
#pragma unroll
    for (int a = 0; a < 4; ++a)
#pragma unroll
        for (int r = 0; r < 4; ++r) rs[a][r] = 0.f;

    int mbase = mchunk + wv * 64;
    bf16x8 Bn0 = Qv[(size_t)(mbase +  0 + c16) * 4 + g];
    bf16x8 Bn1 = Qv[(size_t)(mbase + 16 + c16) * 4 + g];
    bf16x8 Bn2 = Qv[(size_t)(mbase + 32 + c16) * 4 + g];
    bf16x8 Bn3 = Qv[(size_t)(mbase + 48 + c16) * 4 + g];

    const int NIT = NN / SPLITM / 256;  // 4
    for (int it = 0; it < NIT; ++it) {
        bf16x8 B0 = Bn0, B1 = Bn1, B2 = Bn2, B3 = Bn3;
        int mnext = mbase + 256;
        if (it + 1 < NIT) {
            Bn0 = Qv[(size_t)(mnext +  0 + c16) * 4 + g];
            Bn1 = Qv[(size_t)(mnext + 16 + c16) * 4 + g];
            Bn2 = Qv[(size_t)(mnext + 32 + c16) * 4 + g];
            Bn3 = Qv[(size_t)(mnext + 48 + c16) * 4 + g];
        }
#define ROWSTEP(Aa, a)                                                        \
        {                                                                     \
            f32x4 e0 = __builtin_amdgcn_mfma_f32_16x16x32_bf16(Aa, B0, z, 0, 0, 0); \
            f32x4 e1 = __builtin_amdgcn_mfma_f32_16x16x32_bf16(Aa, B1, z, 0, 0, 0); \
            f32x4 e2 = __builtin_amdgcn_mfma_f32_16x16x32_bf16(Aa, B2, z, 0, 0, 0); \
            f32x4 e3 = __builtin_amdgcn_mfma_f32_16x16x32_bf16(Aa, B3, z, 0, 0, 0); \
            _Pragma("unroll")                                                 \
            for (int r = 0; r < 4; ++r)                                       \
                rs[a][r] += (fexp2(e0[r]) + fexp2(e1[r])) + (fexp2(e2[r]) + fexp2(e3[r])); \
        }
        ROWSTEP(A0, 0) ROWSTEP(A1, 1) ROWSTEP(A2, 2) ROWSTEP(A3, 3)
#undef ROWSTEP
        mbase = mnext;
    }
#pragma unroll
    for (int a = 0; a < 4; ++a)
#pragma unroll
        for (int r = 0; r < 4; ++r) {
            float v = rs[a][r];
            v += __shfl_xor(v, 1);
            v += __shfl_xor(v, 2);
            v += __shfl_xor(v, 4);
            v += __shfl_xor(v, 8);
            if (c16 == 0)
                atomicAdd(&rowsumG[(size_t)b * NN + n0 + 16 * a + 4 * g + r], v);
        }
}

// reciprocal of rowsums
__global__ __launch_bounds__(256) void k_recip(const float* __restrict__ rowsumG, float* __restrict__ irsG) {
    int i = blockIdx.x * 256 + threadIdx.x;
    irsG[i] = 1.f / rowsumG[i];
}

// K3: barrier-free, LDS-free main loop. Wave owns (b, m-tile 64, n-chunk 512).
// Writes x_r partials [SPLITN][B][64][N] f32 and csum partials [SPLITN][B][N].
__global__ __launch_bounds__(256, 3) void k_attn(
    const bf16_t* __restrict__ Qb, const bf16_t* __restrict__ XVb,
    const float* __restrict__ irsG,
    float* __restrict__ part, float* __restrict__ cpart)
{
    __shared__ __align__(16) float accL[64 * 68];
    __shared__ float csL[4 * 64];

    int b = blockIdx.z;
    int m0 = blockIdx.x * 64;
    int chunk = blockIdx.y;
    int tid = threadIdx.x;
    int wv = tid >> 6, l = tid & 63;
    int g = l >> 4, c16 = l & 15;

    const bf16x8* Qv = (const bf16x8*)(Qb + (size_t)b * NN * DD);
    const bf16_t* XVbase = XVb + (size_t)b * CP * NN;
    const float* irb = irsG + (size_t)b * NN;

    bf16x8 bq0 = Qv[(size_t)(m0 +  0 + c16) * 4 + g];
    bf16x8 bq1 = Qv[(size_t)(m0 + 16 + c16) * 4 + g];
    bf16x8 bq2 = Qv[(size_t)(m0 + 32 + c16) * 4 + g];
    bf16x8 bq3 = Qv[(size_t)(m0 + 48 + c16) * 4 + g];

    f32x4 z = {0.f, 0.f, 0.f, 0.f};
    f32x4 acc[4][4];
#pragma unroll
    for (int ci = 0; ci < 4; ++ci)
#pragma unroll
        for (int j = 0; j < 4; ++j) acc[ci][j] = z;
    float cs[4] = {0.f, 0.f, 0.f, 0.f};

    // per-lane XV row base pointers (+4g k-offset)
    const bf16_t* xb0 = XVbase + (size_t)( 0 + c16) * NN + 4 * g;
    const bf16_t* xb1 = XVbase + (size_t)(16 + c16) * NN + 4 * g;
    const bf16_t* xb2 = XVbase + (size_t)(32 + c16) * NN + 4 * g;
    const bf16_t* xb3 = XVbase + (size_t)(48 + c16) * NN + 4 * g;

    int n0w = chunk * (NN / SPLITN) + wv * 512;

    for (int it = 0; it < 16; ++it) {
        int n = n0w + it * 32;
        // XV A-frags (direct global, L2-resident; one 64B line per row per iter)
        bf16x8 xv0 = ld_av(xb0 + n);
        bf16x8 xv1 = ld_av(xb1 + n);
        bf16x8 xv2 = ld_av(xb2 + n);
        bf16x8 xv3 = ld_av(xb3 + n);
        // Q A-frags + irs
        bf16x8 a0 = Qv[(size_t)(n + c16) * 4 + g];
        bf16x8 a1 = Qv[(size_t)(n + 16 + c16) * 4 + g];
        f32x4 iv0 = *(const f32x4*)&irb[n + 4 * g];
        f32x4 iv1 = *(const f32x4*)&irb[n + 16 + 4 * g];

        f32x4 E00 = __builtin_amdgcn_mfma_f32_16x16x32_bf16(a0, bq0, z, 0, 0, 0);
        f32x4 E01 = __builtin_amdgcn_mfma_f32_16x16x32_bf16(a0, bq1, z, 0, 0, 0);
        f32x4 E02 = __builtin_amdgcn_mfma_f32_16x16x32_bf16(a0, bq2, z, 0, 0, 0);
        f32x4 E03 = __builtin_amdgcn_mfma_f32_16x16x32_bf16(a0, bq3, z, 0, 0, 0);
        f32x4 E10 = __builtin_amdgcn_mfma_f32_16x16x32_bf16(a1, bq0, z, 0, 0, 0);
        f32x4 E11 = __builtin_amdgcn_mfma_f32_16x16x32_bf16(a1, bq1, z, 0, 0, 0);
        f32x4 E12 = __builtin_amdgcn_mfma_f32_16x16x32_bf16(a1, bq2, z, 0, 0, 0);
        f32x4 E13 = __builtin_amdgcn_mfma_f32_16x16x32_bf16(a1, bq3, z, 0, 0, 0);

        bf16x8 bp0, bp1, bp2, bp3;
#define MKBP(E0v, E1v, bp, jj)                                                \
        {                                                                     \
            float q0[4], q1[4];                                               \
            _Pragma("unroll")                                                 \
            for (int r = 0; r < 4; ++r) {                                     \
                q0[r] = fexp2(E0v[r]) * iv0[r];                               \
                q1[r] = fexp2(E1v[r]) * iv1[r];                               \
            }                                                                 \
            cs[jj] += ((q0[0] + q0[1]) + (q0[2] + q0[3]))                     \
                    + ((q1[0] + q1[1]) + (q1[2] + q1[3]));                    \
            bp = pack8(q0[0], q0[1], q0[2], q0[3], q1[0], q1[1], q1[2], q1[3]); \
        }
        MKBP(E00, E10, bp0, 0)
        MKBP(E01, E11, bp1, 1)
        MKBP(E02, E12, bp2, 2)
        MKBP(E03, E13, bp3, 3)
#undef MKBP

#define PVROW(ci, xv)                                                         \
        acc[ci][0] = __builtin_amdgcn_mfma_f32_16x16x32_bf16(xv, bp0, acc[ci][0], 0, 0, 0); \
        acc[ci][1] = __builtin_amdgcn_mfma_f32_16x16x32_bf16(xv, bp1, acc[ci][1], 0, 0, 0); \
        acc[ci][2] = __builtin_amdgcn_mfma_f32_16x16x32_bf16(xv, bp2, acc[ci][2], 0, 0, 0); \
        acc[ci][3] = __builtin_amdgcn_mfma_f32_16x16x32_bf16(xv, bp3, acc[ci][3], 0, 0, 0);
        PVROW(0, xv0)
        PVROW(1, xv1)
        PVROW(2, xv2)
        PVROW(3, xv3)
#undef PVROW
    }

    // ---- block epilogue: cross-wave reduce, write partials ----
#pragma unroll
    for (int j = 0; j < 4; ++j) {
        cs[j] += __shfl_xor(cs[j], 16);
        cs[j] += __shfl_xor(cs[j], 32);
    }
    if (l < 16) {
#pragma unroll
        for (int j = 0; j < 4; ++j) csL[wv * 64 + 16 * j + l] = cs[j];
    }
    for (int k = 0; k < 4; ++k) {
        if (wv == k) {
#pragma unroll
            for (int ci = 0; ci < 4; ++ci)
#pragma unroll
                for (int j = 0; j < 4; ++j)
#pragma unroll
                    for (int r = 0; r < 4; ++r) {
                        int cc = 16 * ci + 4 * g + r, mm = 16 * j + c16;
                        if (k == 0) accL[cc * 68 + mm] = acc[ci][j][r];
                        else        accL[cc * 68 + mm] += acc[ci][j][r];
                    }
        }
        __syncthreads();
    }
    {
        int c = tid >> 2, m16 = (tid & 3) * 16;
        float* dst = part + (((size_t)chunk * BB + b) * CP + c) * NN + m0 + m16;
        const float* srcp = &accL[c * 68 + m16];
        *(float4*)&dst[0]  = *(const float4*)&srcp[0];
        *(float4*)&dst[4]  = *(const float4*)&srcp[4];
        *(float4*)&dst[8]  = *(const float4*)&srcp[8];
        *(float4*)&dst[12] = *(const float4*)&srcp[12];
    }
    if (tid < 64) {
        float cp = csL[tid] + csL[64 + tid] + csL[128 + tid] + csL[192 + tid];
        cpart[((size_t)chunk * BB + b) * NN + m0 + tid] = cp;
    }
}

// K4: combine partials + L1 renorm + T = pfeat - x_r + t-conv MFMA + Y + BN partials
__global__ __launch_bounds__(256) void k_post(
    const float* __restrict__ part, const float* __restrict__ cpart,
    const float* __restrict__ pfeat, const bf16_t* __restrict__ twb,
    const float* __restrict__ tb, float* __restrict__ Y, float* __restrict__ bnred)
{
    __shared__ __align__(16) float accL[64 * 36];
    __shared__ float invc[32];

    int b = blockIdx.y;
    int m0 = blockIdx.x * 32;
    int tid = threadIdx.x;
    int wv = tid >> 6, l = tid & 63;
    int g = l >> 4, c16 = l & 15;
    f32x4 z = {0.f, 0.f, 0.f, 0.f};

    {
        int c = tid >> 2, m8 = (tid & 3) * 8;
        float4 sa = {0.f, 0.f, 0.f, 0.f}, sb = {0.f, 0.f, 0.f, 0.f};
#pragma unroll
        for (int s = 0; s < SPLITN; ++s) {
            const float* rp = part + (((size_t)s * BB + b) * CP + c) * NN + m0 + m8;
            float4 ta = *(const float4*)rp;
            float4 tb4 = *(const float4*)(rp + 4);
            sa.x += ta.x; sa.y += ta.y; sa.z += ta.z; sa.w += ta.w;
            sb.x += tb4.x; sb.y += tb4.y; sb.z += tb4.z; sb.w += tb4.w;
        }
        *(float4*)&accL[c * 36 + m8] = sa;
        *(float4*)&accL[c * 36 + m8 + 4] = sb;
    }
    if (tid < 32) {
        float cst = 0.f;
#pragma unroll
        for (int s = 0; s < SPLITN; ++s)
            cst += cpart[((size_t)s * BB + b) * NN + m0 + tid];
        invc[tid] = 1.f / (1e-9f + cst);
    }
    __syncthreads();
    {
        int mm = tid & 31, cq = tid >> 5;
        float ic = invc[mm];
#pragma unroll
        for (int k = 0; k < 8; ++k) {
            int cc = cq * 8 + k;
            float pf = pfeat[((size_t)b * CP + cc) * NN + m0 + mm];
            accL[cc * 36 + mm] = pf - accL[cc * 36 + mm] * ic;
        }
    }
    __syncthreads();
    {
        const bf16_t* twr = twb + (size_t)(16 * wv + c16) * 64;
        bf16x8 Aw0 = ld_av(twr + 4 * g);
        bf16x8 Aw1 = ld_av(twr + 32 + 4 * g);
        f32x4 y0 = z, y1 = z;
#pragma unroll
        for (int ck = 0; ck < 2; ++ck) {
            bf16x8 B0, B1;
#pragma unroll
            for (int r = 0; r < 4; ++r) {
                int klo = 32 * ck + 4 * g + r, khi = 32 * ck + 16 + 4 * g + r;
                B0[r]     = (bf16_t)accL[klo * 36 + c16];
                B0[4 + r] = (bf16_t)accL[khi * 36 + c16];
                B1[r]     = (bf16_t)accL[klo * 36 + 16 + c16];
                B1[4 + r] = (bf16_t)accL[khi * 36 + 16 + c16];
            }
            bf16x8 Ac = ck ? Aw1 : Aw0;
            y0 = __builtin_amdgcn_mfma_f32_16x16x32_bf16(Ac, B0, y0, 0, 0, 0);
            y1 = __builtin_amdgcn_mfma_f32_16x16x32_bf16(Ac, B1, y1, 0, 0, 0);
        }
        f32x4 tbv = *(const f32x4*)&tb[16 * wv + 4 * g];
#pragma unroll
        for (int r = 0; r < 4; ++r) {
            int o = 16 * wv + 4 * g + r;
            float ya = y0[r] + tbv[r];
            float yb = y1[r] + tbv[r];
            Y[((size_t)b * CP + o) * NN + m0 + c16] = ya;
            Y[((size_t)b * CP + o) * NN + m0 + 16 + c16] = yb;
            float sv = ya + yb, sq = ya * ya + yb * yb;
            sv += __shfl_xor(sv, 1); sq += __shfl_xor(sq, 1);
            sv += __shfl_xor(sv, 2); sq += __shfl_xor(sq, 2);
            sv += __shfl_xor(sv, 4); sq += __shfl_xor(sq, 4);
            sv += __shfl_xor(sv, 8); sq += __shfl_xor(sq, 8);
            if (c16 == 0) {
                atomicAdd(&bnred[o], sv);
                atomicAdd(&bnred[64 + o], sq);
            }
        }
    }
}

// K5: BN finalize + ReLU + residual
__global__ __launch_bounds__(256) void k_final(
    const float* __restrict__ Y, const float* __restrict__ pfeat,
    const float* __restrict__ gamma, const float* __restrict__ beta,
    const float* __restrict__ bnred, float* __restrict__ out)
{
    int idx = blockIdx.x * 256 + threadIdx.x;  // flat over [B][CP][NN]
    int o = (idx / NN) & (CP - 1);
    const float invcnt = 1.f / (float)(BB * NN);
    float mean = bnred[o] * invcnt;
    float var = bnred[64 + o] * invcnt - mean * mean;
    float y = Y[idx];
    float zz = gamma[o] * (y - mean) * rsqrtf(var + 1e-5f) + beta[o];
    zz = fmaxf(zz, 0.f);
    out[idx] = pfeat[idx] + zz;
}

extern "C" void kernel_launch(void* const* d_in, const int* in_sizes, int n_in,
                              void* d_out, int out_size, void* d_ws, size_t ws_size,
                              hipStream_t stream) {
    const float* pts_img = (const float*)d_in[0];
    const float* img     = (const float*)d_in[1];
    const float* pfeat   = (const float*)d_in[2];
    const float* qkw     = (const float*)d_in[3];
    const float* vw      = (const float*)d_in[4];
    const float* vb      = (const float*)d_in[5];
    const float* tw      = (const float*)d_in[6];
    const float* tb      = (const float*)d_in[7];
    const float* gamma   = (const float*)d_in[8];
    const float* beta    = (const float*)d_in[9];

    // workspace layout (bytes), total ~31.4 MB
    char* base = (char*)d_ws;
    bf16_t* Qb      = (bf16_t*)(base);                  // 1,048,576   [B][N][32]
    bf16_t* XVb     = (bf16_t*)(base + 1048576);        // 2,097,152   [B][64][N]
    bf16_t* twb     = (bf16_t*)(base + 3145728);        // 8,192
    float*  rowsumG = (float*)(base + 3153920);         // 66,048      [B][N]+pad
    float*  bn      = (float*)(base + 3219968);         // 512
    float*  irsG    = (float*)(base + 3220480);         // 66,048
    float*  cpart   = (float*)(base + 3286528);         // 262,144     [SPLITN][B][N]
    float*  Y       = (float*)(base + 3548672);         // 4,194,304   [B][64][N]
    float*  part    = (float*)(base + 7742976);         // 16,777,216  [SPLITN][B][64][N]
    float*  imgT    = (float*)(base + 24520192);        // 8,388,608   [B][HW][64]

    hipMemsetAsync(rowsumG, 0, 66560, stream);  // rowsumG + bn (contiguous)
    k_prep<<<16, 256, 0, stream>>>(tw, twb);
    k_timg<<<dim3((HH * WW) / 64, BB), 256, 0, stream>>>(img, imgT);
    k_fuse<<<(BB * NN) / 16, 256, 0, stream>>>(pts_img, imgT, pfeat, qkw, vw, vb, Qb, XVb);
    k_rowsum<<<dim3(NN / 64, SPLITM, BB), 256, 0, stream>>>(Qb, rowsumG);
    k_recip<<<(BB * NN) / 256, 256, 0, stream>>>(rowsumG, irsG);
    k_attn<<<dim3(NN / 64, SPLITN, BB), 256, 0, stream>>>(Qb, XVb, irsG, part, cpart);
    k_post<<<dim3(NN / 32, BB), 256, 0, stream>>>(part, cpart, pfeat, twb, tb, Y, bn);
    k_final<<<(BB * CP * NN) / 256, 256, 0, stream>>>(Y, pfeat, gamma, beta, bn, (float*)d_out);
}